// Round 7
// baseline (507.976 us; speedup 1.0000x reference)
//
#include <hip/hip_runtime.h>
#include <hip/hip_fp16.h>
#include <math.h>

namespace {
constexpr int S = 192;
constexpr long long S2 = (long long)S * S;
constexpr long long S3 = (long long)S * S2;
constexpr int NB = 4;
constexpr int K = 11;
constexpr int R = 5;
constexpr int HCH = 48;   // A: h-outputs per block (4 chunks)
constexpr int DCH = 48;   // B: d-outputs per block (4 chunks)
constexpr float C1f = 1e-4f;
constexpr float C2f = 9e-4f;

struct GaussW { float g[K]; };

__global__ void k_init(double* acc) { *acc = 0.0; }

__global__ void k_final(const double* __restrict__ acc, float* __restrict__ out) {
  out[0] = (float)(acc[0] / (double)(NB * S3));
}

// ======================= Kernel A =======================
// Fused W+H blur, packed-fp16 pipeline. (a,b) staged as __half2 in LDS
// (18.3 KB double buffer -> 8 blocks/CU); W-blur and H-blur both in pk-fp16
// (per-voxel noise ~1e-3 random sign, averages out in the 28M-voxel mean).
// Fields 0..3 packed 4xfp16 in uint2; field 4 separate fp16.

template <int N, bool GUARD>
__device__ __forceinline__ void loadA(const float* pg, const float* pp, int r0,
                                      int w, __half2 (&lh)[K]) {
#pragma unroll
  for (int j = 0; j < N; ++j) {
    int r = r0 + j;
    bool ok = !GUARD || ((unsigned)r < (unsigned)S);
    float a = ok ? pg[(long long)r * S + w] : 0.f;
    float b = ok ? pp[(long long)r * S + w] : 0.f;
    lh[j] = __floats2half2_rn(a, b);
  }
}

template <int N>
__device__ __forceinline__ void commitA(__half2 (*rb)[208], int w,
                                        const __half2 (&lh)[K]) {
#pragma unroll
  for (int j = 0; j < N; ++j) rb[j][8 + w] = lh[j];
}

template <int NROWS, bool EMITALL>
__device__ __forceinline__ void consumeA(
    const __half2 (*rb)[208], int w, const __half2 (&gh2)[K],
    __half2 (&q01)[K], __half2 (&q23)[K], __half (&q4)[K],
    uint2* p0123, __half* p4, long long obase, int hbase) {
#pragma unroll
  for (int j = 0; j < NROWS; ++j) {
    // W-blur of (a,b,a2,b2,ab) in packed fp16
    __half2 s01 = __floats2half2_rn(0.f, 0.f);
    __half2 s23 = s01;
    __half s4 = __float2half(0.f);
#pragma unroll
    for (int i = 0; i < K; ++i) {
      __half2 ab = rb[j][w + 3 + i];
      s01 = __hfma2(gh2[i], ab, s01);
      __half2 t = __hmul2(gh2[i], ab);      // (g*a, g*b)
      s23 = __hfma2(t, ab, s23);            // (g*a2, g*b2)
      s4 = __hfma(__low2half(t), __high2half(ab), s4);  // g*a*b
    }
    q01[j] = s01; q23[j] = s23; q4[j] = s4;  // ring slot = counter % 11 = j
    if (EMITALL || j == K - 1) {             // compile-time
      __half2 m01 = __floats2half2_rn(0.f, 0.f);
      __half2 m23 = m01;
      __half m4 = __float2half(0.f);
#pragma unroll
      for (int i = 0; i < K; ++i) {
        const int sl = (j + 1 + i) % K;      // compile-time
        m01 = __hfma2(gh2[i], q01[sl], m01);
        m23 = __hfma2(gh2[i], q23[sl], m23);
        m4 = __hfma(__low2half(gh2[i]), q4[sl], m4);
      }
      long long o = obase + (long long)(hbase + j) * S;
      uint2 v;
      v.x = __builtin_bit_cast(unsigned, m01);
      v.y = __builtin_bit_cast(unsigned, m23);
      p0123[o] = v;
      p4[o] = m4;
    }
  }
}

// grid = (dz=S, hchunk=4, n); block = 192 (w). 11-row batches, LDS double
// buffer, loads register-staged one batch ahead (R5-proven schedule with the
// batch-4 guard: rows h0+39..h0+49 reach 193 for h0=144).
__global__ __launch_bounds__(192) void k_blurWH(
    const float* __restrict__ gt, const float* __restrict__ pr,
    uint2* __restrict__ p0123, __half* __restrict__ p4,
    long long in_base, GaussW Wt) {
  __shared__ __half2 rowbuf[2][K][208];  // [8..199] data, pads zero (18.3 KB)
  const int w = threadIdx.x;
  const int dz = blockIdx.x;
  const int h0 = (int)blockIdx.y * HCH;
  const long long n = blockIdx.z;
  const float* pg = gt + in_base + (n * S + dz) * S2;
  const float* pp = pr + in_base + (n * S + dz) * S2;
  const long long obase = (n * S + dz) * S2 + w;

  __half2 gh2[K];
#pragma unroll
  for (int i = 0; i < K; ++i) gh2[i] = __float2half2_rn(Wt.g[i]);

  if (w < 176) {  // zero halo pads of both buffers once
    int j = w >> 4, q = w & 15;
    int idx = (q < 8) ? q : (192 + q);
    rowbuf[0][j][idx] = __floats2half2_rn(0.f, 0.f);
    rowbuf[1][j][idx] = __floats2half2_rn(0.f, 0.f);
  }

  __half2 q01[K], q23[K];
  __half q4[K];
  __half2 lh[K];

  loadA<K, true>(pg, pp, h0 - R, w, lh);               // b0: h0-5..h0+5 (G)
  commitA<K>(rowbuf[0], w, lh);
  __syncthreads();
  loadA<K, false>(pg, pp, h0 + 6, w, lh);              // b1 (max 160: safe)
  consumeA<K, false>(rowbuf[0], w, gh2, q01, q23, q4, p0123, p4, obase, h0 - 10);
  commitA<K>(rowbuf[1], w, lh);
  __syncthreads();
  loadA<K, false>(pg, pp, h0 + 17, w, lh);             // b2 (max 171: safe)
  consumeA<K, true>(rowbuf[1], w, gh2, q01, q23, q4, p0123, p4, obase, h0 + 1);
  commitA<K>(rowbuf[0], w, lh);
  __syncthreads();
  loadA<K, false>(pg, pp, h0 + 28, w, lh);             // b3 (max 182: safe)
  consumeA<K, true>(rowbuf[0], w, gh2, q01, q23, q4, p0123, p4, obase, h0 + 12);
  commitA<K>(rowbuf[1], w, lh);
  __syncthreads();
  loadA<K, true>(pg, pp, h0 + 39, w, lh);              // b4 (max 193: GUARD)
  consumeA<K, true>(rowbuf[1], w, gh2, q01, q23, q4, p0123, p4, obase, h0 + 23);
  commitA<K>(rowbuf[0], w, lh);
  __syncthreads();
  loadA<3, true>(pg, pp, h0 + 50, w, lh);              // b5 tail 3 (GUARD)
  consumeA<K, true>(rowbuf[0], w, gh2, q01, q23, q4, p0123, p4, obase, h0 + 34);
  commitA<3>(rowbuf[1], w, lh);
  __syncthreads();
  consumeA<3, true>(rowbuf[1], w, gh2, q01, q23, q4, p0123, p4, obase, h0 + 45);
}

// ======================= Kernel B =======================

template <int N, bool GUARD>
__device__ __forceinline__ void stageB(const uint2* q0123, const __half* q4,
                                       int plane0, uint2 (&sab)[K], __half (&se)[K]) {
#pragma unroll
  for (int j = 0; j < N; ++j) {
    int d = plane0 + j;
    bool ok = !GUARD || ((unsigned)d < (unsigned)S);
    long long o = (long long)d * S2;
    sab[j] = ok ? q0123[o] : make_uint2(0u, 0u);  // fp16 bits 0 == 0.0
    se[j] = ok ? q4[o] : __float2half(0.f);
  }
}

template <int NOUT>
__device__ __forceinline__ void consumeB(
    const uint2 (&sab)[K], const __half (&se)[K],
    const GaussW& Wt, float2 (&r01)[K], float2 (&r23)[K], float (&r4)[K],
    double& lsum) {
  float fsum = 0.f;
#pragma unroll
  for (int j = 0; j < NOUT; ++j) {
    const int sw = (10 + j) % K;              // compile-time commit slot
    r01[sw] = __half22float2(__builtin_bit_cast(__half2, sab[j].x));
    r23[sw] = __half22float2(__builtin_bit_cast(__half2, sab[j].y));
    r4[sw] = __half2float(se[j]);
    float2 m01 = make_float2(0.f, 0.f), m23 = make_float2(0.f, 0.f);
    float m4 = 0.f;
#pragma unroll
    for (int i = 0; i < K; ++i) {
      const int sl = (j + i) % K;             // compile-time
      float g = Wt.g[i];
      m01.x = fmaf(g, r01[sl].x, m01.x);
      m01.y = fmaf(g, r01[sl].y, m01.y);
      m23.x = fmaf(g, r23[sl].x, m23.x);
      m23.y = fmaf(g, r23[sl].y, m23.y);
      m4 = fmaf(g, r4[sl], m4);
    }
    float mux = m01.x, muy = m01.y, bxx = m23.x, byy = m23.y, bxy = m4;
    float mux2 = mux * mux, muy2 = muy * muy, muxy = mux * muy;
    float sx = bxx - mux2, sy = byy - muy2, sxy = bxy - muxy;
    float num = fmaf(2.f, muxy, C1f) * fmaf(2.f, sxy, C2f);
    float den = (mux2 + muy2 + C1f) * (sx + sy + C2f);
    fsum += 1.f - num * __builtin_amdgcn_rcpf(den);
  }
  lsum += (double)fsum;
}

// D-blur + SSIM + mean-reduce. grid = (h=S, n, dchunk=4); block = 192 (w).
// Register ring of 11 planes, ping-pong staging one 11-batch ahead.
__global__ __launch_bounds__(192) void k_blurD_ssim(
    const uint2* __restrict__ p0123, const __half* __restrict__ p4,
    double* __restrict__ acc, GaussW Wt) {
  const int w = threadIdx.x;
  const int h = blockIdx.x;
  const long long n = blockIdx.y;
  const int d0 = (int)blockIdx.z * DCH;
  const long long base = n * S3 + (long long)h * S + w;
  const uint2* q0123 = p0123 + base;
  const __half* q4 = p4 + base;

  float2 r01[K], r23[K];
  float r4[K];
#pragma unroll
  for (int c = 0; c < K - 1; ++c) {
    int d = d0 - R + c;
    if ((unsigned)d < (unsigned)S) {
      long long o = (long long)d * S2;
      uint2 v = q0123[o];
      r01[c] = __half22float2(__builtin_bit_cast(__half2, v.x));
      r23[c] = __half22float2(__builtin_bit_cast(__half2, v.y));
      r4[c] = __half2float(q4[o]);
    } else {
      r01[c] = make_float2(0.f, 0.f);
      r23[c] = make_float2(0.f, 0.f);
      r4[c] = 0.f;
    }
  }
  r01[K - 1] = make_float2(0.f, 0.f);
  r23[K - 1] = make_float2(0.f, 0.f);
  r4[K - 1] = 0.f;

  uint2 sab0[K], sab1[K];
  __half se0[K], se1[K];
  double lsum = 0.0;

  // plane ranges: d0+5..15, d0+16..26, d0+27..37 (max 181: safe);
  // d0+38..48 and d0+49..52 guarded (max 196).
  stageB<K, false>(q0123, q4, d0 + 5, sab0, se0);   // counters 10..20
  stageB<K, false>(q0123, q4, d0 + 16, sab1, se1);  // counters 21..31
  consumeB<K>(sab0, se0, Wt, r01, r23, r4, lsum);   // t = 0..10
  stageB<K, false>(q0123, q4, d0 + 27, sab0, se0);  // counters 32..42
  consumeB<K>(sab1, se1, Wt, r01, r23, r4, lsum);   // t = 11..21
  stageB<K, true>(q0123, q4, d0 + 38, sab1, se1);   // counters 43..53
  consumeB<K>(sab0, se0, Wt, r01, r23, r4, lsum);   // t = 22..32
  stageB<4, true>(q0123, q4, d0 + 49, sab0, se0);   // counters 54..57
  consumeB<K>(sab1, se1, Wt, r01, r23, r4, lsum);   // t = 33..43
  consumeB<4>(sab0, se0, Wt, r01, r23, r4, lsum);   // t = 44..47

  // block reduction: wave shuffle -> LDS -> one atomic per block
  double v = lsum;
#pragma unroll
  for (int o = 32; o > 0; o >>= 1) v += __shfl_down(v, o, 64);
  __shared__ double wsum[3];
  int lane = threadIdx.x & 63, wv = threadIdx.x >> 6;
  if (lane == 0) wsum[wv] = v;
  __syncthreads();
  if (threadIdx.x == 0) atomicAdd(acc, wsum[0] + wsum[1] + wsum[2]);
}

}  // namespace

extern "C" void kernel_launch(void* const* d_in, const int* in_sizes, int n_in,
                              void* d_out, int out_size, void* d_ws, size_t ws_size,
                              hipStream_t stream) {
  (void)in_sizes; (void)n_in; (void)out_size;
  const float* gt = (const float*)d_in[0];
  const float* pr = (const float*)d_in[1];
  float* out = (float*)d_out;
  double* acc = (double*)d_ws;

  GaussW W;
  {
    double gg[K], sum = 0.0;
    for (int i = 0; i < K; ++i) {
      double x = (double)(i - K / 2);
      gg[i] = exp(-(x * x) / (2.0 * 1.5 * 1.5)) / (sqrt(2.0 * M_PI) * 1.5);
      sum += gg[i];
    }
    for (int i = 0; i < K; ++i) W.g[i] = (float)(gg[i] / sum);
  }

  auto run = [&](long long base_n, int nb) {
    size_t vox = (size_t)nb * S3;
    uint2* p0123 = (uint2*)((char*)d_ws + 256);
    __half* p4 = (__half*)(p0123 + vox);
    k_blurWH<<<dim3(S, S / HCH, nb), dim3(192), 0, stream>>>(
        gt, pr, p0123, p4, base_n * S3, W);
    k_blurD_ssim<<<dim3(S, nb, S / DCH), dim3(192), 0, stream>>>(
        p0123, p4, acc, W);
  };
  auto need = [](int nb) { return (size_t)256 + (size_t)nb * S3 * 10; };  // 8+2 B/voxel

  k_init<<<dim3(1), dim3(1), 0, stream>>>(acc);
  if (ws_size >= need(4)) {
    run(0, 4);
  } else if (ws_size >= need(2)) {
    run(0, 2);
    run(2, 2);
  } else {
    for (int g = 0; g < NB; ++g) run(g, 1);
  }
  k_final<<<dim3(1), dim3(1), 0, stream>>>(acc, out);
}